// Round 1
// baseline (174.395 us; speedup 1.0000x reference)
//
#include <hip/hip_runtime.h>

// SparseNeuralNetwork: 256 independent sub-nets j = i*16 + o (i,o in [0,16)).
//   layer0: v[k] = relu(W0[16j+k, i] * x[b,i] + b0[16j+k]),   k in [0,16)
//   layer1: u[m] = relu(b1[8j+m] + sum_k W1[8j+m, 16j+k] * v[k]), m in [0,8)
//   out[b,o] = b2[o] + sum_i sum_m W2[o, 8j+m] * u[m]
//
// Thread = (b, o). Lanes vary b; o is wave-uniform (readfirstlane -> SGPR),
// so all weight addresses are wave-uniform -> scalar s_load on the SMEM pipe,
// VALU does only the 152 FMAs + relus per sub-net.

#define BATCH   8192
#define IN_DIM  16
#define OUT_DIM 16
#define H0      16
#define H1      8
#define D0      (IN_DIM * OUT_DIM * H0)   // 4096
#define D1      (IN_DIM * OUT_DIM * H1)   // 2048

__global__ __launch_bounds__(256, 4) void sparse_mlp_kernel(
    const float* __restrict__ x,
    const float* __restrict__ W0, const float* __restrict__ b0,
    const float* __restrict__ W1, const float* __restrict__ b1,
    const float* __restrict__ W2, const float* __restrict__ b2,
    float* __restrict__ out)
{
    const int lane = threadIdx.x & 63;
    const int wv   = threadIdx.x >> 6;            // wave id in block (0..3)
    const int b    = blockIdx.x * 64 + lane;      // batch element
    // o is identical across the wave's 64 lanes; pin it to an SGPR so the
    // compiler's uniformity analysis scalarizes every weight load.
    const int o    = __builtin_amdgcn_readfirstlane((int)(blockIdx.y * 4 + wv));

    float acc = b2[o];

    #pragma unroll 1
    for (int i = 0; i < IN_DIM; ++i) {
        const int j = i * 16 + o;                 // sub-network index
        const float xv = x[b * IN_DIM + i];

        // layer 0: 16 neurons, each reads the single unmasked column i
        float v[H0];
        #pragma unroll
        for (int k = 0; k < H0; ++k) {
            const int r = j * H0 + k;             // row in W0 / b0
            float t = fmaf(W0[r * IN_DIM + i], xv, b0[r]);
            v[k] = t > 0.0f ? t : 0.0f;
        }

        // layer 1 (8x16 dense block) fused with layer-2 contribution
        #pragma unroll
        for (int m = 0; m < H1; ++m) {
            const int r1 = j * H1 + m;            // row in W1 / b1
            const float* __restrict__ w1row = W1 + (size_t)r1 * D0 + j * H0;
            float u = b1[r1];
            #pragma unroll
            for (int k = 0; k < H0; ++k)
                u = fmaf(w1row[k], v[k], u);
            u = u > 0.0f ? u : 0.0f;
            acc = fmaf(W2[o * D1 + j * H1 + m], u, acc);
        }
    }

    out[b * OUT_DIM + o] = acc;
}

extern "C" void kernel_launch(void* const* d_in, const int* in_sizes, int n_in,
                              void* d_out, int out_size, void* d_ws, size_t ws_size,
                              hipStream_t stream) {
    const float* x  = (const float*)d_in[0];
    const float* W0 = (const float*)d_in[1];
    const float* b0 = (const float*)d_in[2];
    const float* W1 = (const float*)d_in[3];
    const float* b1 = (const float*)d_in[4];
    const float* W2 = (const float*)d_in[5];
    const float* b2 = (const float*)d_in[6];
    float* out = (float*)d_out;

    dim3 grid(BATCH / 64, OUT_DIM / 4);   // 128 x 4 = 512 blocks
    sparse_mlp_kernel<<<grid, 256, 0, stream>>>(x, W0, b0, W1, b1, W2, b2, out);
}

// Round 2
// 102.052 us; speedup vs baseline: 1.7089x; 1.7089x over previous
//
#include <hip/hip_runtime.h>

// SparseNeuralNetwork: 256 independent sub-nets j = i*16 + o (i,o in [0,16)).
//   layer0: v[k] = relu(W0[16j+k, i] * x[b,i] + b0[16j+k]),   k in [0,16)
//   layer1: u[m] = relu(b1[8j+m] + sum_k W1[8j+m, 16j+k] * v[k]), m in [0,8)
//   out[b,o] = b2[o] + sum_i sum_m W2[o, 8j+m] * u[m]
//
// R2: stage the block's weight slices (4 o-values, 45 KB) in LDS once, then
// fully-unrolled compute. Weight LDS addresses are wave-uniform -> broadcast
// ds_read (conflict-free); x lives in registers via 4 coalesced float4 loads.
// Target: VALU-bound (~5 us floor for 318M fp32 FMA on the vector ALU).

#define BATCH   8192
#define IN_DIM  16
#define OUT_DIM 16
#define H0      16
#define H1      8
#define D0      (IN_DIM * OUT_DIM * H0)   // 4096
#define D1      (IN_DIM * OUT_DIM * H1)   // 2048

__global__ __launch_bounds__(256, 2) void sparse_mlp_kernel(
    const float* __restrict__ x,
    const float* __restrict__ W0, const float* __restrict__ b0,
    const float* __restrict__ W1, const float* __restrict__ b1,
    const float* __restrict__ W2, const float* __restrict__ b2,
    float* __restrict__ out)
{
    __shared__ float sW0[4][16][16];      // [wv][i][k]   4 KB
    __shared__ float sB0[4][16][16];      // [wv][i][k]   4 KB
    __shared__ float sW1[4][16][8][16];   // [wv][i][m][k] 32 KB
    __shared__ float sB1[4][16][8];       // [wv][i][m]   2 KB
    __shared__ float sW2[4][16][8];       // [wv][i][m]   2 KB

    const int t  = threadIdx.x;
    const int o0 = blockIdx.y * 4;

    // ---- stage weights (block-diagonal gather) ----
    // W1 block rows: 4 o * 16 i * 8 m rows of 16 contiguous floats
    #pragma unroll
    for (int f = t; f < 8192; f += 256) {
        const int w = f >> 11, i = (f >> 7) & 15, m = (f >> 4) & 7, k = f & 15;
        const int j = i * 16 + (o0 + w);
        sW1[w][i][m][k] = W1[(size_t)(j * H1 + m) * D0 + j * H0 + k];
    }
    #pragma unroll
    for (int f = t; f < 1024; f += 256) {
        const int w = f >> 8, i = (f >> 4) & 15, k = f & 15;
        const int r = (i * 16 + (o0 + w)) * H0 + k;   // row in W0/b0
        sW0[w][i][k] = W0[r * IN_DIM + i];
        sB0[w][i][k] = b0[r];
    }
    #pragma unroll
    for (int f = t; f < 512; f += 256) {
        const int w = f >> 7, i = (f >> 3) & 15, m = f & 7;
        const int j = i * 16 + (o0 + w);
        sB1[w][i][m] = b1[j * H1 + m];
        sW2[w][i][m] = W2[(o0 + w) * D1 + j * H1 + m];
    }
    __syncthreads();

    // ---- compute: thread = (b, o); lanes vary b, o wave-uniform ----
    const int lane = t & 63;
    const int wv   = t >> 6;
    const int b    = blockIdx.x * 64 + lane;
    const int o    = o0 + wv;

    // x[b, 0..15] -> registers, coalesced 64 B per lane
    float xr[16];
    {
        const float4* xp = (const float4*)(x + (size_t)b * IN_DIM);
        float4 a0 = xp[0], a1 = xp[1], a2 = xp[2], a3 = xp[3];
        xr[0]=a0.x; xr[1]=a0.y; xr[2]=a0.z;  xr[3]=a0.w;
        xr[4]=a1.x; xr[5]=a1.y; xr[6]=a1.z;  xr[7]=a1.w;
        xr[8]=a2.x; xr[9]=a2.y; xr[10]=a2.z; xr[11]=a2.w;
        xr[12]=a3.x;xr[13]=a3.y;xr[14]=a3.z; xr[15]=a3.w;
    }

    float acc = b2[o];

    #pragma unroll
    for (int i = 0; i < IN_DIM; ++i) {
        const float xi = xr[i];
        float v[H0];
        #pragma unroll
        for (int k = 0; k < H0; ++k)
            v[k] = fmaxf(fmaf(sW0[wv][i][k], xi, sB0[wv][i][k]), 0.0f);
        #pragma unroll
        for (int m = 0; m < H1; ++m) {
            float u = sB1[wv][i][m];
            #pragma unroll
            for (int k = 0; k < H0; ++k)
                u = fmaf(sW1[wv][i][m][k], v[k], u);
            acc = fmaf(sW2[wv][i][m], fmaxf(u, 0.0f), acc);
        }
    }

    out[(size_t)b * OUT_DIM + o] = acc;
}

extern "C" void kernel_launch(void* const* d_in, const int* in_sizes, int n_in,
                              void* d_out, int out_size, void* d_ws, size_t ws_size,
                              hipStream_t stream) {
    const float* x  = (const float*)d_in[0];
    const float* W0 = (const float*)d_in[1];
    const float* b0 = (const float*)d_in[2];
    const float* W1 = (const float*)d_in[3];
    const float* b1 = (const float*)d_in[4];
    const float* W2 = (const float*)d_in[5];
    const float* b2 = (const float*)d_in[6];
    float* out = (float*)d_out;

    dim3 grid(BATCH / 64, OUT_DIM / 4);   // 128 x 4 = 512 blocks
    sparse_mlp_kernel<<<grid, 256, 0, stream>>>(x, W0, b0, W1, b1, W2, b2, out);
}